// Round 5
// baseline (95.105 us; speedup 1.0000x reference)
//
#include <hip/hip_runtime.h>
#include <hip/hip_bf16.h>

namespace {

constexpr int Bc = 2, Hc = 16, Lc = 2048, Dc = 128;
constexpr int KVBLK = 64;
constexpr int BH  = Bc * Hc;      // 32
constexpr int NKT = Lc / KVBLK;   // 32
constexpr int QB  = 128;          // q rows per block
constexpr int NQT = Lc / QB;      // 16
// 1/sqrt(128) * log2(e)  (softmax in exp2 domain)
constexpr float SCALE = 0.08838834764831845f * 1.4426950408889634f;

using f32x4   = __attribute__((ext_vector_type(4))) float;
using f32x16  = __attribute__((ext_vector_type(16))) float;
using short8  = __attribute__((ext_vector_type(8))) short;

union FragU { short8 v; short4 h[2]; };
union PFU  { short8 v; unsigned u[4]; };

__device__ inline short f2bf(float f) {
  unsigned u = __builtin_bit_cast(unsigned, f);
  u += 0x7fffu + ((u >> 16) & 1u);          // RNE
  return (short)(u >> 16);
}

__device__ inline void gload_lds16(const short* g, short* l) {
  __builtin_amdgcn_global_load_lds(
      (const __attribute__((address_space(1))) void*)g,
      (__attribute__((address_space(3))) void*)l, 16, 0, 0);
}

// ============ fused pre-pass: K and V fp32 -> bf16 in MFMA-ready layouts ============
// K tiles (16 KB each, 64 rows x 256B): logical granule g of row holds k-elems
// {chunk*16+hi*4+0..3, chunk*16+8+hi*4+0..3}, chunk=g>>1, hi=g&1 (one b128 = one
// 32x32x16 A-fragment); physical granule x = g ^ (row&7) (bank swizzle).
// V tiles: transposed to [d][kv] with the same kv-permutation + swizzle.
__global__ __launch_bounds__(256) void conv_kv(const float* __restrict__ Kg,
                                               const float* __restrict__ Vg,
                                               short* __restrict__ Kw,
                                               short* __restrict__ Vw) {
  __shared__ short Vs[64 * 130];
  const int b = blockIdx.x;
  if (b < 4096) {
    int tid = b * 256 + threadIdx.x;            // 1,048,576 total
    int x   = tid & 15;
    int row = (tid >> 4) & 63;
    int tb  = tid >> 10;
    int g   = x ^ (row & 7);
    int chunk = g >> 1, hi = g & 1;
    const float* src = Kg + ((size_t)tb * 64 + row) * 128 + chunk * 16 + hi * 4;
    float4 a = *(const float4*)src;
    float4 c = *(const float4*)(src + 8);
    short8 v;
    v[0] = f2bf(a.x); v[1] = f2bf(a.y); v[2] = f2bf(a.z); v[3] = f2bf(a.w);
    v[4] = f2bf(c.x); v[5] = f2bf(c.y); v[6] = f2bf(c.z); v[7] = f2bf(c.w);
    *(short8*)(Kw + (size_t)tb * 8192 + row * 128 + x * 8) = v;
  } else {
    int tb  = b - 4096;                         // bh*32 + t
    int tid = threadIdx.x;
    const float* vt = Vg + (size_t)tb * 8192;
#pragma unroll
    for (int p = 0; p < 8; ++p) {
      int g  = p * 256 + tid;
      int kv = g >> 5;
      int c4 = g & 31;
      float4 v = *((const float4*)vt + g);
      short* d = &Vs[kv * 130 + c4 * 4];
      d[0] = f2bf(v.x); d[1] = f2bf(v.y); d[2] = f2bf(v.z); d[3] = f2bf(v.w);
    }
    __syncthreads();
#pragma unroll
    for (int p = 0; p < 4; ++p) {
      int gg = p * 256 + tid;
      int d  = gg >> 3;
      int x  = gg & 7;
      int g  = x ^ (d & 7);
      int chunk = g >> 1, hi = g & 1;
      int k0 = chunk * 16 + hi * 4;
      short8 o;
#pragma unroll
      for (int j = 0; j < 4; ++j) o[j]     = Vs[(k0 + j)     * 130 + d];
#pragma unroll
      for (int j = 0; j < 4; ++j) o[4 + j] = Vs[(k0 + 8 + j) * 130 + d];
      *(short8*)(Vw + (size_t)tb * 8192 + d * 64 + x * 8) = o;
    }
  }
}

// ============== main attention: 32x32x16 MFMA, two-tile pipelined PV ==============
__global__ __launch_bounds__(256, 2) void attn_fwd5(
    const float* __restrict__ Qg, const short* __restrict__ Kw,
    const short* __restrict__ Vw, float* __restrict__ Og) {

  __shared__ __align__(16) short K2[2][8192];   // 32 KB  (K double-buffer)
  __shared__ __align__(16) short V3[3][8192];   // 48 KB  (V triple-buffer)

  const int tid  = threadIdx.x;
  const int wave = tid >> 6;
  const int lane = tid & 63;
  const int hi   = lane >> 5;                 // k-half select
  const int ln   = lane & 31;
  const int sw   = (ln & 7) << 4;             // XOR swizzle (row&7 == ln&7)

  const int bid = blockIdx.x;
  const int bh  = bid & (BH - 1);             // bid%8 == bh%8 -> head-per-XCD L2 affinity
  const int r5  = bid >> 5;                   // 0..15
  const int qt  = (bid < 256) ? (NQT - 1 - r5) : (r5 - 8);   // anti-correlated load
  const int q0w = qt * QB + wave * 32;

  const float* Qp  = Qg + (size_t)bh * Lc * Dc;
  float*       Op  = Og + (size_t)bh * Lc * Dc;
  const short* Kwp = Kw + (size_t)bh * NKT * 8192;
  const short* Vwp = Vw + (size_t)bh * NKT * 8192;

  // ---- preload Q fragments (B-operand), pre-scaled ----
  short8 qf[8];
  {
    const float* qrow = Qp + (size_t)(q0w + ln) * Dc + hi * 4;
#pragma unroll
    for (int ks = 0; ks < 8; ++ks) {
      float4 a = *(const float4*)(qrow + ks * 16);
      float4 b = *(const float4*)(qrow + ks * 16 + 8);
      short8 v;
      v[0] = f2bf(a.x * SCALE); v[1] = f2bf(a.y * SCALE);
      v[2] = f2bf(a.z * SCALE); v[3] = f2bf(a.w * SCALE);
      v[4] = f2bf(b.x * SCALE); v[5] = f2bf(b.y * SCALE);
      v[6] = f2bf(b.z * SCALE); v[7] = f2bf(b.w * SCALE);
      qf[ks] = v;
    }
  }

  float m_run = -1e30f, l_run = 0.0f;
  f32x16 oacc[4];
#pragma unroll
  for (int nt = 0; nt < 4; ++nt)
#pragma unroll
    for (int r = 0; r < 16; ++r) oacc[nt][r] = 0.0f;

  const int ntiles = 2 * (qt + 1);
  const int tlast  = min(ntiles - 1, (q0w + 31) >> 6);   // wave's last unmasked tile

  auto stage = [&](int t, int kb, int vb) {
    const short* gk = Kwp + (size_t)t * 8192 + tid * 8;
    const short* gv = Vwp + (size_t)t * 8192 + tid * 8;
    short* lk = &K2[kb][tid * 8];
    short* lv = &V3[vb][tid * 8];
#pragma unroll
    for (int i = 0; i < 4; ++i) gload_lds16(gk + i * 2048, lk + i * 2048);
#pragma unroll
    for (int i = 0; i < 4; ++i) gload_lds16(gv + i * 2048, lv + i * 2048);
  };

  stage(0, 0, 0);
  int vb_prev = 2, vb_cur = 0, vb_next = 1;   // V buffer of tiles t-1, t, t+1
  PFU pf[4];

  for (int t = 0; t < ntiles; ++t) {
    const int cur = t & 1;
    __builtin_amdgcn_s_barrier();             // all reads of bufs we overwrite done
    if (t + 1 < ntiles) {
      stage(t + 1, cur ^ 1, vb_next);
      asm volatile("s_waitcnt vmcnt(8)" ::: "memory");   // tile t's 8 loads landed
    } else {
      asm volatile("s_waitcnt vmcnt(0)" ::: "memory");
    }
    __builtin_amdgcn_s_barrier();             // all waves see tile t's data
    __builtin_amdgcn_sched_barrier(0);

    const bool do_t = (t <= tlast);
    const bool do_pv = (t >= 1) && (t - 1 <= tlast);
    const int kv0 = t * KVBLK;

    // ---- QK(t): S^T = K*Q^T. D col=q=ln, kv row = (r&3)+8*(r>>2)+4*hi (+32 for s1)
    f32x16 s0, s1;
    if (do_t) {
      const char* Kl = (const char*)&K2[cur][0];
#pragma unroll
      for (int r = 0; r < 16; ++r) { s0[r] = 0.0f; s1[r] = 0.0f; }
      __builtin_amdgcn_s_setprio(1);
#pragma unroll
      for (int ks = 0; ks < 8; ++ks) {
        FragU a0, a1;
        int col = (ks * 32 + hi * 16) ^ sw;
        a0.v = *(const short8*)(Kl + ln * 256        + col);
        a1.v = *(const short8*)(Kl + (32 + ln) * 256 + col);
        s0 = __builtin_amdgcn_mfma_f32_32x32x16_bf16(a0.v, qf[ks], s0, 0, 0, 0);
        s1 = __builtin_amdgcn_mfma_f32_32x32x16_bf16(a1.v, qf[ks], s1, 0, 0, 0);
      }
      __builtin_amdgcn_s_setprio(0);
    }

    // ---- PV(t-1): independent of QK(t) -> MFMA pipe stays fed ----
    if (do_pv) {
      const char* Vl = (const char*)&V3[vb_prev][0];
      __builtin_amdgcn_s_setprio(1);
#pragma unroll
      for (int nt = 0; nt < 4; ++nt) {
        const char* vrow = Vl + (nt * 32 + ln) * 128;
#pragma unroll
        for (int kc = 0; kc < 4; ++kc) {
          FragU b;
          b.v = *(const short8*)(vrow + ((kc * 32 + hi * 16) ^ sw));
          oacc[nt] = __builtin_amdgcn_mfma_f32_32x32x16_bf16(pf[kc].v, b.v, oacc[nt], 0, 0, 0);
        }
      }
      __builtin_amdgcn_s_setprio(0);
    }

    // ---- softmax(t) with defer-max; pack P via v_cvt_pk_bf16_f32 ----
    if (do_t) {
      if (kv0 + 63 > q0w) {                   // diagonal masking
        const int qg = q0w + ln;
#pragma unroll
        for (int r = 0; r < 16; ++r) {
          int kvr = kv0 + (r & 3) + 8 * (r >> 2) + 4 * hi;
          if (kvr > qg)      s0[r] = -1e30f;
          if (kvr + 32 > qg) s1[r] = -1e30f;
        }
      }
      // 4 parallel max chains (depth ~9, v_max3-friendly)
      float ma = s0[0], mb = s0[8], mc = s1[0], md = s1[8];
#pragma unroll
      for (int r = 1; r < 8; ++r) {
        ma = fmaxf(ma, s0[r]); mb = fmaxf(mb, s0[8 + r]);
        mc = fmaxf(mc, s1[r]); md = fmaxf(md, s1[8 + r]);
      }
      float mx = fmaxf(fmaxf(ma, mb), fmaxf(mc, md));
      mx = fmaxf(mx, __shfl_xor(mx, 32));

      if (!__all(mx - m_run <= 8.0f)) {       // rescale path (rare)
        float mnew = fmaxf(m_run, mx);
        float corr = exp2f(m_run - mnew);
        m_run = mnew;
        l_run *= corr;
#pragma unroll
        for (int r = 0; r < 16; ++r) {
          int qrow = (r & 3) + 8 * (r >> 2) + 4 * hi;
          float c = __shfl(corr, qrow);
#pragma unroll
          for (int nt = 0; nt < 4; ++nt) oacc[nt][r] *= c;
        }
      }

      float rsp[4] = {0.f, 0.f, 0.f, 0.f};
#pragma unroll
      for (int kc = 0; kc < 4; ++kc) {
#pragma unroll
        for (int w = 0; w < 4; ++w) {
          int e = kc * 8 + w * 2;
          float v0 = (kc < 2) ? (float)s0[e]     : (float)s1[e - 16];
          float v1 = (kc < 2) ? (float)s0[e + 1] : (float)s1[e - 15];
          float e0 = exp2f(v0 - m_run);
          float e1 = exp2f(v1 - m_run);
          rsp[w] += e0 + e1;
          asm("v_cvt_pk_bf16_f32 %0, %1, %2" : "=v"(pf[kc].u[w]) : "v"(e0), "v"(e1));
        }
      }
      float rs = (rsp[0] + rsp[1]) + (rsp[2] + rsp[3]);
      rs += __shfl_xor(rs, 32);
      l_run += rs;
    }

    int tmp = vb_prev; vb_prev = vb_cur; vb_cur = vb_next; vb_next = tmp;
  }

  // ---- drain: PV(tlast) for waves whose last tile was the final iteration ----
  if (tlast == ntiles - 1) {
    const char* Vl = (const char*)&V3[vb_prev][0];
#pragma unroll
    for (int nt = 0; nt < 4; ++nt) {
      const char* vrow = Vl + (nt * 32 + ln) * 128;
#pragma unroll
      for (int kc = 0; kc < 4; ++kc) {
        FragU b;
        b.v = *(const short8*)(vrow + ((kc * 32 + hi * 16) ^ sw));
        oacc[nt] = __builtin_amdgcn_mfma_f32_32x32x16_bf16(pf[kc].v, b.v, oacc[nt], 0, 0, 0);
      }
    }
  }

  // ---- epilogue: O row q=(r&3)+8*(r>>2)+4*hi, col d = nt*32+ln ----
  float linv = 1.0f / l_run;
#pragma unroll
  for (int r = 0; r < 16; ++r) {
    int qrow = (r & 3) + 8 * (r >> 2) + 4 * hi;
    float il = __shfl(linv, qrow);
    float* orow = Op + (size_t)(q0w + qrow) * Dc + ln;
#pragma unroll
    for (int nt = 0; nt < 4; ++nt)
      orow[nt * 32] = oacc[nt][r] * il;
  }
}

// ===================== fallback (ws too small): R1 kernel =====================
__device__ inline unsigned packbf(float a, float b) {
  return (unsigned)(unsigned short)f2bf(a) | ((unsigned)(unsigned short)f2bf(b) << 16);
}

__global__ __launch_bounds__(256, 2) void attn_fb(
    const float* __restrict__ Qg, const float* __restrict__ Kg,
    const float* __restrict__ Vg, float* __restrict__ Og) {
  __shared__ __align__(16) short Klds[KVBLK * Dc];
  __shared__ __align__(16) short Vt[Dc * 68];
  const int tid = threadIdx.x, wave = tid >> 6, lane = tid & 63;
  const int lg = lane >> 4, lr = lane & 15;
  const int bid = blockIdx.x;
  const int bh = bid & (BH - 1);
  const int qt = 31 - (bid >> 5);
  const int q0w = qt * 64 + wave * 16;
  const float* Qp = Qg + (size_t)bh * Lc * Dc;
  const float* Kp = Kg + (size_t)bh * Lc * Dc;
  const float* Vp = Vg + (size_t)bh * Lc * Dc;
  float* Op = Og + (size_t)bh * Lc * Dc;
  short8 qf[4];
  {
    const float* qrow = Qp + (size_t)(q0w + lr) * Dc;
#pragma unroll
    for (int dc = 0; dc < 4; ++dc) {
      float4 a = *(const float4*)(qrow + dc * 32 + lg * 4);
      float4 b = *(const float4*)(qrow + dc * 32 + 16 + lg * 4);
      short8 v;
      v[0]=f2bf(a.x*SCALE); v[1]=f2bf(a.y*SCALE); v[2]=f2bf(a.z*SCALE); v[3]=f2bf(a.w*SCALE);
      v[4]=f2bf(b.x*SCALE); v[5]=f2bf(b.y*SCALE); v[6]=f2bf(b.z*SCALE); v[7]=f2bf(b.w*SCALE);
      qf[dc] = v;
    }
  }
  const f32x4 zero4 = {0.f,0.f,0.f,0.f};
  float m_run = -1e30f, l_run = 0.0f;
  f32x4 oacc[8];
#pragma unroll
  for (int dt = 0; dt < 8; ++dt) oacc[dt] = zero4;
  const int ntiles = qt + 1, c4 = tid & 31, rK = tid >> 5;
  for (int t = 0; t < ntiles; ++t) {
    const int kv0 = t * KVBLK;
    __syncthreads();
#pragma unroll
    for (int p = 0; p < 8; ++p) {
      int row = rK + p * 8;
      float4 k4 = *(const float4*)(Kp + (size_t)(kv0 + row) * Dc + c4 * 4);
      short4 pk; pk.x=f2bf(k4.x); pk.y=f2bf(k4.y); pk.z=f2bf(k4.z); pk.w=f2bf(k4.w);
      *(short4*)((char*)Klds + row * 256 + ((c4 * 8) ^ ((row & 7) << 4))) = pk;
    }
#pragma unroll
    for (int p = 0; p < 4; ++p) {
      int r0 = rK * 2 + p * 16;
      float4 v0 = *(const float4*)(Vp + (size_t)(kv0 + r0) * Dc + c4 * 4);
      float4 v1 = *(const float4*)(Vp + (size_t)(kv0 + r0 + 1) * Dc + c4 * 4);
      char* vb = (char*)Vt + r0 * 2;
      *(unsigned*)(vb + (c4*4+0)*136) = packbf(v0.x, v1.x);
      *(unsigned*)(vb + (c4*4+1)*136) = packbf(v0.y, v1.y);
      *(unsigned*)(vb + (c4*4+2)*136) = packbf(v0.z, v1.z);
      *(unsigned*)(vb + (c4*4+3)*136) = packbf(v0.w, v1.w);
    }
    __syncthreads();
    f32x4 st[4];
#pragma unroll
    for (int mt = 0; mt < 4; ++mt) st[mt] = zero4;
#pragma unroll
    for (int dc = 0; dc < 4; ++dc)
#pragma unroll
      for (int mt = 0; mt < 4; ++mt) {
        int row = mt * 16 + lr, sw2 = (row & 7) << 4;
        FragU a;
        a.h[0] = *(short4*)((char*)Klds + row*256 + ((dc*64      + lg*8) ^ sw2));
        a.h[1] = *(short4*)((char*)Klds + row*256 + ((dc*64 + 32 + lg*8) ^ sw2));
        st[mt] = __builtin_amdgcn_mfma_f32_16x16x32_bf16(a.v, qf[dc], st[mt], 0, 0, 0);
      }
    if (t == ntiles - 1) {
      const int qg = q0w + lr;
#pragma unroll
      for (int mt = 0; mt < 4; ++mt)
#pragma unroll
        for (int r = 0; r < 4; ++r)
          if (kv0 + mt * 16 + lg * 4 + r > qg) st[mt][r] = -1e30f;
    }
    float mx = st[0][0];
#pragma unroll
    for (int mt = 0; mt < 4; ++mt)
#pragma unroll
      for (int r = 0; r < 4; ++r) mx = fmaxf(mx, st[mt][r]);
    mx = fmaxf(mx, __shfl_xor(mx, 16));
    mx = fmaxf(mx, __shfl_xor(mx, 32));
    float mnew = fmaxf(m_run, mx);
    float corr = exp2f(m_run - mnew);
    m_run = mnew;
    float pr[4][4]; float rs = 0.0f;
#pragma unroll
    for (int mt = 0; mt < 4; ++mt)
#pragma unroll
      for (int r = 0; r < 4; ++r) { float e = exp2f(st[mt][r] - mnew); pr[mt][r] = e; rs += e; }
    rs += __shfl_xor(rs, 16);
    rs += __shfl_xor(rs, 32);
    l_run = l_run * corr + rs;
#pragma unroll
    for (int r = 0; r < 4; ++r) {
      float c = __shfl(corr, (lane & 48) + lg * 4 + r);
#pragma unroll
      for (int dt = 0; dt < 8; ++dt) oacc[dt][r] *= c;
    }
    short8 pf2[2];
#pragma unroll
    for (int c = 0; c < 2; ++c) {
      short8 v;
      v[0]=f2bf(pr[2*c][0]); v[1]=f2bf(pr[2*c][1]); v[2]=f2bf(pr[2*c][2]); v[3]=f2bf(pr[2*c][3]);
      v[4]=f2bf(pr[2*c+1][0]); v[5]=f2bf(pr[2*c+1][1]); v[6]=f2bf(pr[2*c+1][2]); v[7]=f2bf(pr[2*c+1][3]);
      pf2[c] = v;
    }
#pragma unroll
    for (int dt = 0; dt < 8; ++dt) {
      int rowb = (dt * 16 + lr) * 136;
#pragma unroll
      for (int c = 0; c < 2; ++c) {
        FragU b;
        b.h[0] = *(short4*)((char*)Vt + rowb + c*64      + lg*8);
        b.h[1] = *(short4*)((char*)Vt + rowb + c*64 + 32 + lg*8);
        oacc[dt] = __builtin_amdgcn_mfma_f32_16x16x32_bf16(pf2[c], b.v, oacc[dt], 0, 0, 0);
      }
    }
  }
#pragma unroll
  for (int r = 0; r < 4; ++r) {
    float li = __shfl(l_run, (lane & 48) + lg * 4 + r);
    float inv = 1.0f / li;
    float* orow = Op + (size_t)(q0w + lg * 4 + r) * Dc;
#pragma unroll
    for (int dt = 0; dt < 8; ++dt) orow[dt * 16 + lr] = oacc[dt][r] * inv;
  }
}

} // namespace

extern "C" void kernel_launch(void* const* d_in, const int* in_sizes, int n_in,
                              void* d_out, int out_size, void* d_ws, size_t ws_size,
                              hipStream_t stream) {
  const float* Q = (const float*)d_in[0];
  const float* K = (const float*)d_in[1];
  const float* V = (const float*)d_in[2];
  float* O = (float*)d_out;
  const size_t elems = (size_t)BH * Lc * Dc;          // 8.39M per tensor
  const size_t need  = 2 * elems * sizeof(short);     // 33.5 MB
  if (ws_size >= need) {
    short* Kw = (short*)d_ws;
    short* Vw = Kw + elems;
    conv_kv<<<dim3(4096 + 1024), dim3(256), 0, stream>>>(K, V, Kw, Vw);
    attn_fwd5<<<dim3(BH * NQT), dim3(256), 0, stream>>>(Q, Kw, Vw, O);
  } else {
    attn_fb<<<dim3(BH * NKT), dim3(256), 0, stream>>>(Q, K, V, O);
  }
}